// Round 5
// baseline (269.636 us; speedup 1.0000x reference)
//
#include <hip/hip_runtime.h>

#define D 96          // feature dim
#define D4 24         // float4s per row
#define XSTR 100      // Xs row stride in floats

// ======================= CSR build =======================

__global__ void hist_kernel(const int* __restrict__ dst, int* __restrict__ deg, int E) {
    int e = blockIdx.x * blockDim.x + threadIdx.x;
    if (e < E) atomicAdd(&deg[dst[e]], 1);
}

__global__ void block_sums(const int* __restrict__ deg, int* __restrict__ bsums, int N) {
    __shared__ int s[256];
    int t = threadIdx.x;
    int base = blockIdx.x * 1024 + t * 4;
    int sum = 0;
#pragma unroll
    for (int j = 0; j < 4; ++j) { int i = base + j; if (i < N) sum += deg[i]; }
    s[t] = sum; __syncthreads();
    for (int off = 128; off > 0; off >>= 1) {
        if (t < off) s[t] += s[t + off];
        __syncthreads();
    }
    if (t == 0) bsums[blockIdx.x] = s[0];
}

__global__ void scan_small(const int* __restrict__ bsums, int* __restrict__ boff,
                           int* __restrict__ total_out, int nb) {
    if (threadIdx.x == 0 && blockIdx.x == 0) {
        int acc = 0;
        for (int i = 0; i < nb; ++i) { boff[i] = acc; acc += bsums[i]; }
        *total_out = acc;
    }
}

__global__ void scan_write(const int* __restrict__ deg, const int* __restrict__ boff,
                           int* __restrict__ rowptr, int N) {
    __shared__ int s[256];
    int t = threadIdx.x;
    int base = blockIdx.x * 1024 + t * 4;
    int v[4]; int tsum = 0;
#pragma unroll
    for (int j = 0; j < 4; ++j) { int i = base + j; v[j] = (i < N) ? deg[i] : 0; tsum += v[j]; }
    s[t] = tsum; __syncthreads();
    for (int off = 1; off < 256; off <<= 1) {
        int x = (t >= off) ? s[t - off] : 0;
        __syncthreads();
        s[t] += x;
        __syncthreads();
    }
    int excl = s[t] - tsum + boff[blockIdx.x];
#pragma unroll
    for (int j = 0; j < 4; ++j) { int i = base + j; if (i < N) rowptr[i] = excl; excl += v[j]; }
}

// bucket fill: cursor pre-initialized (copy of rowptr)
__global__ void fill_edges(const int* __restrict__ src, const int* __restrict__ dst,
                           int* __restrict__ cursor, int* __restrict__ esrc, int E) {
    int e = blockIdx.x * blockDim.x + threadIdx.x;
    if (e >= E) return;
    int pos = atomicAdd(&cursor[dst[e]], 1);
    esrc[pos] = src[e];
}

// ======================= fused GIN layer =======================
// Block = 64 nodes, 512 threads (8 waves), LDS = Xs only (25.6 KB).
// Gather: 8 threads/node (r=tid>>3, q=tid&7), 3 float4 per thread, edge loop x4
//         unrolled -> 12 independent 16B loads in flight per thread.
// MLP:    wave wq owns cols wq*12..+11 (W loads wave-uniform -> scalar); lane=row.
__global__ __launch_bounds__(512) void gin_layer_fused(
    const float* __restrict__ X, const int* __restrict__ rowptr,
    const int* __restrict__ esrc, const float* __restrict__ eps_p,
    const float* __restrict__ Wa, const float* __restrict__ ba,
    const float* __restrict__ Wb, const float* __restrict__ bb,
    float* __restrict__ Y, int N) {
    __shared__ float Xs[64 * XSTR];    // 25600 B

    int tid = threadIdx.x;
    int R0 = blockIdx.x * 64;

    // ---------- gather ----------
    {
        int r = tid >> 3, q = tid & 7;           // node r, f4-slot q
        int v = R0 + r;
        float4 g[3];
        if (v < N) {
            const float4* X4 = (const float4*)X;
            float s = 1.0f + eps_p[0];
            int base = v * D4;
#pragma unroll
            for (int k = 0; k < 3; ++k) {
                float4 x = X4[base + k * 8 + q];     // 8 q-lanes -> 128B contiguous
                g[k] = make_float4(x.x * s, x.y * s, x.z * s, x.w * s);
            }
            int e = rowptr[v], e1 = rowptr[v + 1];
            for (; e + 3 < e1; e += 4) {
                int u0 = esrc[e] * D4, u1 = esrc[e + 1] * D4;
                int u2 = esrc[e + 2] * D4, u3 = esrc[e + 3] * D4;
#pragma unroll
                for (int k = 0; k < 3; ++k) {
                    float4 m0 = X4[u0 + k * 8 + q];
                    float4 m1 = X4[u1 + k * 8 + q];
                    float4 m2 = X4[u2 + k * 8 + q];
                    float4 m3 = X4[u3 + k * 8 + q];
                    g[k].x += (m0.x + m1.x) + (m2.x + m3.x);
                    g[k].y += (m0.y + m1.y) + (m2.y + m3.y);
                    g[k].z += (m0.z + m1.z) + (m2.z + m3.z);
                    g[k].w += (m0.w + m1.w) + (m2.w + m3.w);
                }
            }
            for (; e < e1; ++e) {
                int u = esrc[e] * D4;
#pragma unroll
                for (int k = 0; k < 3; ++k) {
                    float4 m = X4[u + k * 8 + q];
                    g[k].x += m.x; g[k].y += m.y; g[k].z += m.z; g[k].w += m.w;
                }
            }
        } else {
#pragma unroll
            for (int k = 0; k < 3; ++k) g[k] = make_float4(0.f, 0.f, 0.f, 0.f);
        }
#pragma unroll
        for (int k = 0; k < 3; ++k)
            *(float4*)&Xs[r * XSTR + (k * 8 + q) * 4] = g[k];
    }
    __syncthreads();

    // ---------- MLP ----------
    int lane = tid & 63;                                       // row
    int c0 = __builtin_amdgcn_readfirstlane(tid >> 6) * 12;    // wave-uniform col base

    // GEMMa
    float acc[12];
#pragma unroll
    for (int j = 0; j < 12; ++j) acc[j] = ba[c0 + j];
#pragma unroll 2
    for (int k0 = 0; k0 < D; k0 += 4) {
        float4 xv = *(const float4*)&Xs[lane * XSTR + k0];
        const float* xf = (const float*)&xv;
#pragma unroll
        for (int kk = 0; kk < 4; ++kk) {
            float x = xf[kk];
            const float* wr = &Wa[(k0 + kk) * D + c0];          // wave-uniform
#pragma unroll
            for (int j = 0; j < 12; ++j) acc[j] = fmaf(x, wr[j], acc[j]);
        }
    }
    __syncthreads();

    // h = relu -> Xs (wave writes its 12-col slice of every row; disjoint)
#pragma unroll
    for (int j = 0; j < 12; j += 4) {
        float4 h = make_float4(fmaxf(acc[j + 0], 0.f), fmaxf(acc[j + 1], 0.f),
                               fmaxf(acc[j + 2], 0.f), fmaxf(acc[j + 3], 0.f));
        *(float4*)&Xs[lane * XSTR + c0 + j] = h;
    }
    __syncthreads();

    // GEMMb
    float acc2[12];
#pragma unroll
    for (int j = 0; j < 12; ++j) acc2[j] = bb[c0 + j];
#pragma unroll 2
    for (int k0 = 0; k0 < D; k0 += 4) {
        float4 xv = *(const float4*)&Xs[lane * XSTR + k0];
        const float* xf = (const float*)&xv;
#pragma unroll
        for (int kk = 0; kk < 4; ++kk) {
            float x = xf[kk];
            const float* wr = &Wb[(k0 + kk) * D + c0];
#pragma unroll
            for (int j = 0; j < 12; ++j) acc2[j] = fmaf(x, wr[j], acc2[j]);
        }
    }
    __syncthreads();

    // relu -> Xs, then coalesced copy-out
#pragma unroll
    for (int j = 0; j < 12; j += 4) {
        float4 o = make_float4(fmaxf(acc2[j + 0], 0.f), fmaxf(acc2[j + 1], 0.f),
                               fmaxf(acc2[j + 2], 0.f), fmaxf(acc2[j + 3], 0.f));
        *(float4*)&Xs[lane * XSTR + c0 + j] = o;
    }
    __syncthreads();
    {
        int r = tid >> 3, q = tid & 7;
        int v = R0 + r;
        if (v < N) {
            float4* Y4 = (float4*)Y;
#pragma unroll
            for (int k = 0; k < 3; ++k)
                Y4[v * D4 + k * 8 + q] = *(const float4*)&Xs[r * XSTR + (k * 8 + q) * 4];
        }
    }
}

// ======================= fallback-path kernels (R1, proven) =======================

__global__ void init_scale(const float* __restrict__ x, const float* __restrict__ eps_p,
                           float* __restrict__ y, int n4) {
    float s = 1.0f + eps_p[0];
    const float4* x4 = (const float4*)x;
    float4* y4 = (float4*)y;
    int i = blockIdx.x * blockDim.x + threadIdx.x;
    int stride = gridDim.x * blockDim.x;
    for (; i < n4; i += stride) {
        float4 v = x4[i];
        v.x *= s; v.y *= s; v.z *= s; v.w *= s;
        y4[i] = v;
    }
}

__global__ void scatter_add(const float* __restrict__ feat, const int* __restrict__ src,
                            const int* __restrict__ dst, float* __restrict__ agg, int E) {
    int t = blockIdx.x * blockDim.x + threadIdx.x;
    int total = E * D4;
    if (t >= total) return;
    int e = t / D4;
    int g = t - e * D4;
    int s = src[e];
    int d = dst[e];
    const float4* f4 = (const float4*)feat;
    float4 v = f4[s * D4 + g];
    float* out = agg + d * D + g * 4;
    atomicAdd(out + 0, v.x);
    atomicAdd(out + 1, v.y);
    atomicAdd(out + 2, v.z);
    atomicAdd(out + 3, v.w);
}

__global__ __launch_bounds__(256) void gemm_relu(const float* __restrict__ X,
                                                 const float* __restrict__ W,
                                                 const float* __restrict__ bias,
                                                 float* __restrict__ Y, int N) {
    __shared__ float Ws[D * D];
    __shared__ float Xs2[64 * XSTR];
    int tid = threadIdx.x;
    const float4* W4 = (const float4*)W;
    float4* Ws4 = (float4*)Ws;
#pragma unroll
    for (int i = 0; i < 9; ++i) Ws4[tid + i * 256] = W4[tid + i * 256];
    int R0 = blockIdx.x * 64;
    const float4* X4 = (const float4*)X;
    int base4 = R0 * D4;
    int lim4 = N * D4;
#pragma unroll
    for (int i = 0; i < 6; ++i) {
        int f = tid + i * 256;
        int row = f / D4;
        int col4 = f - row * D4;
        int gi = base4 + f;
        float4 v = make_float4(0.f, 0.f, 0.f, 0.f);
        if (gi < lim4) v = X4[gi];
        *(float4*)&Xs2[row * XSTR + col4 * 4] = v;
    }
    __syncthreads();
    int r = tid >> 2;
    int c0 = (tid & 3) * 24;
    float acc[24];
#pragma unroll
    for (int j = 0; j < 24; ++j) acc[j] = bias[c0 + j];
#pragma unroll 4
    for (int k = 0; k < D; ++k) {
        float xv = Xs2[r * XSTR + k];
        const float* wrow = &Ws[k * D + c0];
#pragma unroll
        for (int j = 0; j < 24; ++j) acc[j] += xv * wrow[j];
    }
    int row = R0 + r;
    if (row < N) {
        float* yr = Y + row * D + c0;
#pragma unroll
        for (int j = 0; j < 24; j += 4) {
            float4 v = make_float4(fmaxf(acc[j + 0], 0.f), fmaxf(acc[j + 1], 0.f),
                                   fmaxf(acc[j + 2], 0.f), fmaxf(acc[j + 3], 0.f));
            *(float4*)&yr[j] = v;
        }
    }
}

// ======================= launch =======================

extern "C" void kernel_launch(void* const* d_in, const int* in_sizes, int n_in,
                              void* d_out, int out_size, void* d_ws, size_t ws_size,
                              hipStream_t stream) {
    const float* feat = (const float*)d_in[0];
    const int*   src  = (const int*)d_in[1];
    const int*   dst  = (const int*)d_in[2];
    const float* eps1 = (const float*)d_in[3];
    const float* W1a  = (const float*)d_in[4];
    const float* b1a  = (const float*)d_in[5];
    const float* W1b  = (const float*)d_in[6];
    const float* b1b  = (const float*)d_in[7];
    const float* eps2 = (const float*)d_in[8];
    const float* W2a  = (const float*)d_in[9];
    const float* b2a  = (const float*)d_in[10];
    const float* W2b  = (const float*)d_in[11];
    const float* b2b  = (const float*)d_in[12];

    int N = in_sizes[0] / D;     // 50000
    int E = in_sizes[1];         // 800000

    float* out = (float*)d_out;

    char* w = (char*)d_ws;
    size_t off = 0;
    auto carve = [&](size_t bytes) -> void* {
        void* p = w + off;
        off += (bytes + 255) & ~(size_t)255;
        return p;
    };
    float* A      = (float*)carve((size_t)N * D * sizeof(float));
    int*   rowptr = (int*)carve((size_t)(N + 1) * sizeof(int));
    int*   deg    = (int*)carve((size_t)N * sizeof(int));
    int*   cursor = (int*)carve((size_t)N * sizeof(int));
    int*   esrc   = (int*)carve((size_t)E * sizeof(int));
    int nb = (N + 1023) / 1024;
    int*   bsums  = (int*)carve((size_t)nb * sizeof(int));
    int*   boff   = (int*)carve((size_t)nb * sizeof(int));
    bool csr_ok = (off <= ws_size);

    int n4 = N * D4;
    int eGrid = (E + 255) / 256;
    int layerGrid = (N + 63) / 64;

    if (csr_ok) {
        // ---- CSR build ----
        hipMemsetAsync(deg, 0, (size_t)N * sizeof(int), stream);
        hist_kernel<<<eGrid, 256, 0, stream>>>(dst, deg, E);
        block_sums<<<nb, 256, 0, stream>>>(deg, bsums, N);
        scan_small<<<1, 64, 0, stream>>>(bsums, boff, rowptr + N, nb);
        scan_write<<<nb, 256, 0, stream>>>(deg, boff, rowptr, N);
        hipMemcpyAsync(cursor, rowptr, (size_t)N * sizeof(int),
                       hipMemcpyDeviceToDevice, stream);
        fill_edges<<<eGrid, 256, 0, stream>>>(src, dst, cursor, esrc, E);

        // ---- layer 1 -> A, layer 2 -> out ----
        gin_layer_fused<<<layerGrid, 512, 0, stream>>>(feat, rowptr, esrc, eps1,
                                                       W1a, b1a, W1b, b1b, A, N);
        gin_layer_fused<<<layerGrid, 512, 0, stream>>>(A, rowptr, esrc, eps2,
                                                       W2a, b2a, W2b, b2b, out, N);
    } else {
        // ---- fallback: R1 atomic-scatter path ----
        int initGrid = (n4 + 255) / 256;
        int scatGrid = (E * D4 + 255) / 256;
        int gemmGrid = (N + 63) / 64;
        init_scale<<<initGrid, 256, 0, stream>>>(feat, eps1, A, n4);
        scatter_add<<<scatGrid, 256, 0, stream>>>(feat, src, dst, A, E);
        gemm_relu<<<gemmGrid, 256, 0, stream>>>(A, W1a, b1a, out, N);
        gemm_relu<<<gemmGrid, 256, 0, stream>>>(out, W1b, b1b, A, N);
        init_scale<<<initGrid, 256, 0, stream>>>(A, eps2, out, n4);
        scatter_add<<<scatGrid, 256, 0, stream>>>(A, src, dst, out, E);
        gemm_relu<<<gemmGrid, 256, 0, stream>>>(out, W2a, b2a, A, N);
        gemm_relu<<<gemmGrid, 256, 0, stream>>>(A, W2b, b2b, out, N);
    }
}

// Round 6
// 230.612 us; speedup vs baseline: 1.1692x; 1.1692x over previous
//
#include <hip/hip_runtime.h>

#define D 96          // feature dim
#define D4 24         // float4s per row
#define XSTR 100      // Xs row stride in floats
typedef unsigned int uint;
typedef unsigned short ushort;

// ---------- bf16 helpers (RNE) ----------
__device__ __forceinline__ ushort f2bf(float f) {
    uint u = __float_as_uint(f);
    u = (u + 0x7FFFu + ((u >> 16) & 1u)) >> 16;
    return (ushort)u;
}
__device__ __forceinline__ uint pack2(float a, float b) {
    return (uint)f2bf(a) | ((uint)f2bf(b) << 16);
}
// add 8 bf16 (one uint4) into a[0..7]
__device__ __forceinline__ void add8(float* a, uint4 c) {
    a[0] += __uint_as_float(c.x << 16);
    a[1] += __uint_as_float(c.x & 0xFFFF0000u);
    a[2] += __uint_as_float(c.y << 16);
    a[3] += __uint_as_float(c.y & 0xFFFF0000u);
    a[4] += __uint_as_float(c.z << 16);
    a[5] += __uint_as_float(c.z & 0xFFFF0000u);
    a[6] += __uint_as_float(c.w << 16);
    a[7] += __uint_as_float(c.w & 0xFFFF0000u);
}

// X (fp32, [N,96]) -> Xb (bf16 chunks, [N,12] x uint4)
__global__ void to_bf16(const float4* __restrict__ X4, uint4* __restrict__ Xb4, int nchunk) {
    int i = blockIdx.x * blockDim.x + threadIdx.x;
    if (i >= nchunk) return;
    float4 a = X4[2 * i], b = X4[2 * i + 1];
    uint4 o;
    o.x = pack2(a.x, a.y); o.y = pack2(a.z, a.w);
    o.z = pack2(b.x, b.y); o.w = pack2(b.z, b.w);
    Xb4[i] = o;
}

// ======================= CSR build =======================

__global__ void hist_kernel(const int* __restrict__ dst, int* __restrict__ deg, int E) {
    int e = blockIdx.x * blockDim.x + threadIdx.x;
    if (e < E) atomicAdd(&deg[dst[e]], 1);
}

__global__ void block_sums(const int* __restrict__ deg, int* __restrict__ bsums, int N) {
    __shared__ int s[256];
    int t = threadIdx.x;
    int base = blockIdx.x * 1024 + t * 4;
    int sum = 0;
#pragma unroll
    for (int j = 0; j < 4; ++j) { int i = base + j; if (i < N) sum += deg[i]; }
    s[t] = sum; __syncthreads();
    for (int off = 128; off > 0; off >>= 1) {
        if (t < off) s[t] += s[t + off];
        __syncthreads();
    }
    if (t == 0) bsums[blockIdx.x] = s[0];
}

__global__ void scan_small(const int* __restrict__ bsums, int* __restrict__ boff,
                           int* __restrict__ total_out, int nb) {
    if (threadIdx.x == 0 && blockIdx.x == 0) {
        int acc = 0;
        for (int i = 0; i < nb; ++i) { boff[i] = acc; acc += bsums[i]; }
        *total_out = acc;
    }
}

__global__ void scan_write(const int* __restrict__ deg, const int* __restrict__ boff,
                           int* __restrict__ rowptr, int N) {
    __shared__ int s[256];
    int t = threadIdx.x;
    int base = blockIdx.x * 1024 + t * 4;
    int v[4]; int tsum = 0;
#pragma unroll
    for (int j = 0; j < 4; ++j) { int i = base + j; v[j] = (i < N) ? deg[i] : 0; tsum += v[j]; }
    s[t] = tsum; __syncthreads();
    for (int off = 1; off < 256; off <<= 1) {
        int x = (t >= off) ? s[t - off] : 0;
        __syncthreads();
        s[t] += x;
        __syncthreads();
    }
    int excl = s[t] - tsum + boff[blockIdx.x];
#pragma unroll
    for (int j = 0; j < 4; ++j) { int i = base + j; if (i < N) rowptr[i] = excl; excl += v[j]; }
}

__global__ void fill_edges(const int* __restrict__ src, const int* __restrict__ dst,
                           int* __restrict__ cursor, int* __restrict__ esrc, int E) {
    int e = blockIdx.x * blockDim.x + threadIdx.x;
    if (e >= E) return;
    int pos = atomicAdd(&cursor[dst[e]], 1);
    esrc[pos] = src[e];
}

// ======================= fused GIN layer =======================
// Block = 64 nodes, 256 threads. Gather: 4 threads/node (r=tid>>2, q=tid&3),
// thread q owns cols [24q,24q+24). Neighbors read from bf16 (3 x uint4/edge/thread)
// when BF16, else fp32 (6 x float4). Self-term always fp32. MLP: wave-uniform W
// (scalar loads), lane=row. Epilogue: fp32 out coalesced; optional bf16 copy.
template <bool BF16>
__global__ __launch_bounds__(256) void gin_layer_fused(
    const float* __restrict__ X, const uint4* __restrict__ Xb,
    const int* __restrict__ rowptr, const int* __restrict__ esrc,
    const float* __restrict__ eps_p,
    const float* __restrict__ Wa, const float* __restrict__ ba,
    const float* __restrict__ Wb, const float* __restrict__ bb,
    float* __restrict__ Y, uint4* __restrict__ Yb, int N) {
    __shared__ float Xs[64 * XSTR];    // 25600 B

    int tid = threadIdx.x;
    int R0 = blockIdx.x * 64;

    // ---------- gather ----------
    {
        int r = tid >> 2, q = tid & 3;
        int v = R0 + r;
        float a[24];
        if (v < N) {
            const float4* X4 = (const float4*)X;
            float s = 1.0f + eps_p[0];
#pragma unroll
            for (int i = 0; i < 6; ++i) {               // self, fp32, cols 24q..24q+23
                float4 x = X4[v * D4 + 6 * q + i];
                a[4*i+0] = s*x.x; a[4*i+1] = s*x.y; a[4*i+2] = s*x.z; a[4*i+3] = s*x.w;
            }
            int e = rowptr[v], e1 = rowptr[v + 1];
            if (BF16) {
                int cb = 3 * q;                          // chunk base within row (12 chunks)
                for (; e + 1 < e1; e += 2) {
                    const uint4* r0 = Xb + (size_t)esrc[e] * 12 + cb;
                    const uint4* r1 = Xb + (size_t)esrc[e + 1] * 12 + cb;
                    uint4 c00 = r0[0], c01 = r0[1], c02 = r0[2];
                    uint4 c10 = r1[0], c11 = r1[1], c12 = r1[2];
                    add8(a + 0, c00); add8(a + 8, c01); add8(a + 16, c02);
                    add8(a + 0, c10); add8(a + 8, c11); add8(a + 16, c12);
                }
                if (e < e1) {
                    const uint4* r0 = Xb + (size_t)esrc[e] * 12 + cb;
                    add8(a + 0, r0[0]); add8(a + 8, r0[1]); add8(a + 16, r0[2]);
                }
            } else {
                for (; e < e1; ++e) {
                    int u = esrc[e] * D4 + 6 * q;
#pragma unroll
                    for (int i = 0; i < 6; ++i) {
                        float4 m = X4[u + i];
                        a[4*i+0] += m.x; a[4*i+1] += m.y; a[4*i+2] += m.z; a[4*i+3] += m.w;
                    }
                }
            }
        } else {
#pragma unroll
            for (int j = 0; j < 24; ++j) a[j] = 0.f;
        }
#pragma unroll
        for (int i = 0; i < 6; ++i)
            *(float4*)&Xs[r * XSTR + q * 24 + 4 * i] =
                make_float4(a[4*i], a[4*i+1], a[4*i+2], a[4*i+3]);
    }
    __syncthreads();

    // ---------- MLP ----------
    int lane = tid & 63;
    int c0 = __builtin_amdgcn_readfirstlane(tid >> 6) * 24;   // wave-uniform col base

    float acc[24];
#pragma unroll
    for (int j = 0; j < 24; ++j) acc[j] = ba[c0 + j];
#pragma unroll 2
    for (int k0 = 0; k0 < D; k0 += 4) {
        float4 xv = *(const float4*)&Xs[lane * XSTR + k0];
        const float* xf = (const float*)&xv;
#pragma unroll
        for (int kk = 0; kk < 4; ++kk) {
            float x = xf[kk];
            const float* wr = &Wa[(k0 + kk) * D + c0];          // wave-uniform -> scalar
#pragma unroll
            for (int j = 0; j < 24; ++j) acc[j] = fmaf(x, wr[j], acc[j]);
        }
    }
    __syncthreads();

#pragma unroll
    for (int j = 0; j < 24; j += 4) {
        float4 h = make_float4(fmaxf(acc[j + 0], 0.f), fmaxf(acc[j + 1], 0.f),
                               fmaxf(acc[j + 2], 0.f), fmaxf(acc[j + 3], 0.f));
        *(float4*)&Xs[lane * XSTR + c0 + j] = h;
    }
    __syncthreads();

    float acc2[24];
#pragma unroll
    for (int j = 0; j < 24; ++j) acc2[j] = bb[c0 + j];
#pragma unroll 2
    for (int k0 = 0; k0 < D; k0 += 4) {
        float4 xv = *(const float4*)&Xs[lane * XSTR + k0];
        const float* xf = (const float*)&xv;
#pragma unroll
        for (int kk = 0; kk < 4; ++kk) {
            float x = xf[kk];
            const float* wr = &Wb[(k0 + kk) * D + c0];
#pragma unroll
            for (int j = 0; j < 24; ++j) acc2[j] = fmaf(x, wr[j], acc2[j]);
        }
    }
    __syncthreads();

#pragma unroll
    for (int j = 0; j < 24; j += 4) {
        float4 o = make_float4(fmaxf(acc2[j + 0], 0.f), fmaxf(acc2[j + 1], 0.f),
                               fmaxf(acc2[j + 2], 0.f), fmaxf(acc2[j + 3], 0.f));
        *(float4*)&Xs[lane * XSTR + c0 + j] = o;
    }
    __syncthreads();

    // fp32 copy-out (coalesced: 64B contiguous per 4-lane group)
    {
        int r = tid >> 2, q = tid & 3;
        int v = R0 + r;
        if (v < N) {
            float4* Y4 = (float4*)Y;
#pragma unroll
            for (int k = 0; k < 6; ++k)
                Y4[v * D4 + k * 4 + q] = *(const float4*)&Xs[r * XSTR + (k * 4 + q) * 4];
        }
    }
    // bf16 copy-out (fully coalesced chunk mapping)
    if (Yb) {
#pragma unroll
        for (int k = 0; k < 3; ++k) {
            int c = tid + 256 * k;          // 0..767
            int row = c / 12, cic = c - row * 12;
            int v = R0 + row;
            if (v < N) {
                const float* p = &Xs[row * XSTR + cic * 8];
                float4 f0 = *(const float4*)p;
                float4 f1 = *(const float4*)(p + 4);
                uint4 o;
                o.x = pack2(f0.x, f0.y); o.y = pack2(f0.z, f0.w);
                o.z = pack2(f1.x, f1.y); o.w = pack2(f1.z, f1.w);
                Yb[(size_t)v * 12 + cic] = o;
            }
        }
    }
}

// ======================= fallback-path kernels (R1, proven) =======================

__global__ void init_scale(const float* __restrict__ x, const float* __restrict__ eps_p,
                           float* __restrict__ y, int n4) {
    float s = 1.0f + eps_p[0];
    const float4* x4 = (const float4*)x;
    float4* y4 = (float4*)y;
    int i = blockIdx.x * blockDim.x + threadIdx.x;
    int stride = gridDim.x * blockDim.x;
    for (; i < n4; i += stride) {
        float4 v = x4[i];
        v.x *= s; v.y *= s; v.z *= s; v.w *= s;
        y4[i] = v;
    }
}

__global__ void scatter_add(const float* __restrict__ feat, const int* __restrict__ src,
                            const int* __restrict__ dst, float* __restrict__ agg, int E) {
    int t = blockIdx.x * blockDim.x + threadIdx.x;
    int total = E * D4;
    if (t >= total) return;
    int e = t / D4;
    int g = t - e * D4;
    int s = src[e];
    int d = dst[e];
    const float4* f4 = (const float4*)feat;
    float4 v = f4[s * D4 + g];
    float* out = agg + d * D + g * 4;
    atomicAdd(out + 0, v.x);
    atomicAdd(out + 1, v.y);
    atomicAdd(out + 2, v.z);
    atomicAdd(out + 3, v.w);
}

__global__ __launch_bounds__(256) void gemm_relu(const float* __restrict__ X,
                                                 const float* __restrict__ W,
                                                 const float* __restrict__ bias,
                                                 float* __restrict__ Y, int N) {
    __shared__ float Ws[D * D];
    __shared__ float Xs2[64 * XSTR];
    int tid = threadIdx.x;
    const float4* W4 = (const float4*)W;
    float4* Ws4 = (float4*)Ws;
#pragma unroll
    for (int i = 0; i < 9; ++i) Ws4[tid + i * 256] = W4[tid + i * 256];
    int R0 = blockIdx.x * 64;
    const float4* X4 = (const float4*)X;
    int base4 = R0 * D4;
    int lim4 = N * D4;
#pragma unroll
    for (int i = 0; i < 6; ++i) {
        int f = tid + i * 256;
        int row = f / D4;
        int col4 = f - row * D4;
        int gi = base4 + f;
        float4 v = make_float4(0.f, 0.f, 0.f, 0.f);
        if (gi < lim4) v = X4[gi];
        *(float4*)&Xs2[row * XSTR + col4 * 4] = v;
    }
    __syncthreads();
    int r = tid >> 2;
    int c0 = (tid & 3) * 24;
    float acc[24];
#pragma unroll
    for (int j = 0; j < 24; ++j) acc[j] = bias[c0 + j];
#pragma unroll 4
    for (int k = 0; k < D; ++k) {
        float xv = Xs2[r * XSTR + k];
        const float* wrow = &Ws[k * D + c0];
#pragma unroll
        for (int j = 0; j < 24; ++j) acc[j] += xv * wrow[j];
    }
    int row = R0 + r;
    if (row < N) {
        float* yr = Y + row * D + c0;
#pragma unroll
        for (int j = 0; j < 24; j += 4) {
            float4 v = make_float4(fmaxf(acc[j + 0], 0.f), fmaxf(acc[j + 1], 0.f),
                                   fmaxf(acc[j + 2], 0.f), fmaxf(acc[j + 3], 0.f));
            *(float4*)&yr[j] = v;
        }
    }
}

// ======================= launch =======================

extern "C" void kernel_launch(void* const* d_in, const int* in_sizes, int n_in,
                              void* d_out, int out_size, void* d_ws, size_t ws_size,
                              hipStream_t stream) {
    const float* feat = (const float*)d_in[0];
    const int*   src  = (const int*)d_in[1];
    const int*   dst  = (const int*)d_in[2];
    const float* eps1 = (const float*)d_in[3];
    const float* W1a  = (const float*)d_in[4];
    const float* b1a  = (const float*)d_in[5];
    const float* W1b  = (const float*)d_in[6];
    const float* b1b  = (const float*)d_in[7];
    const float* eps2 = (const float*)d_in[8];
    const float* W2a  = (const float*)d_in[9];
    const float* b2a  = (const float*)d_in[10];
    const float* W2b  = (const float*)d_in[11];
    const float* b2b  = (const float*)d_in[12];

    int N = in_sizes[0] / D;     // 50000
    int E = in_sizes[1];         // 800000

    float* out = (float*)d_out;

    char* w = (char*)d_ws;
    size_t off = 0;
    auto carve = [&](size_t bytes) -> void* {
        void* p = w + off;
        off += (bytes + 255) & ~(size_t)255;
        return p;
    };
    // CSR essentials first
    float* A      = (float*)carve((size_t)N * D * sizeof(float));
    int*   rowptr = (int*)carve((size_t)(N + 1) * sizeof(int));
    int*   deg    = (int*)carve((size_t)N * sizeof(int));
    int*   cursor = (int*)carve((size_t)N * sizeof(int));
    int*   esrc   = (int*)carve((size_t)E * sizeof(int));
    int nb = (N + 1023) / 1024;
    int*   bsums  = (int*)carve((size_t)nb * sizeof(int));
    int*   boff   = (int*)carve((size_t)nb * sizeof(int));
    bool csr_ok = (off <= ws_size);
    // bf16 extras
    uint4* featb  = (uint4*)carve((size_t)N * 12 * sizeof(uint4));  // 9.6 MB
    uint4* Ab     = (uint4*)carve((size_t)N * 12 * sizeof(uint4));  // 9.6 MB
    bool bf16_ok = (off <= ws_size);

    int n4 = N * D4;
    int eGrid = (E + 255) / 256;
    int layerGrid = (N + 63) / 64;

    if (csr_ok) {
        // ---- CSR build ----
        hipMemsetAsync(deg, 0, (size_t)N * sizeof(int), stream);
        hist_kernel<<<eGrid, 256, 0, stream>>>(dst, deg, E);
        block_sums<<<nb, 256, 0, stream>>>(deg, bsums, N);
        scan_small<<<1, 64, 0, stream>>>(bsums, boff, rowptr + N, nb);
        scan_write<<<nb, 256, 0, stream>>>(deg, boff, rowptr, N);
        hipMemcpyAsync(cursor, rowptr, (size_t)N * sizeof(int),
                       hipMemcpyDeviceToDevice, stream);
        fill_edges<<<eGrid, 256, 0, stream>>>(src, dst, cursor, esrc, E);

        if (bf16_ok) {
            int nchunk = N * 12;
            to_bf16<<<(nchunk + 255) / 256, 256, 0, stream>>>((const float4*)feat, featb, nchunk);
            gin_layer_fused<true><<<layerGrid, 256, 0, stream>>>(
                feat, featb, rowptr, esrc, eps1, W1a, b1a, W1b, b1b, A, Ab, N);
            gin_layer_fused<true><<<layerGrid, 256, 0, stream>>>(
                A, Ab, rowptr, esrc, eps2, W2a, b2a, W2b, b2b, out, nullptr, N);
        } else {
            gin_layer_fused<false><<<layerGrid, 256, 0, stream>>>(
                feat, nullptr, rowptr, esrc, eps1, W1a, b1a, W1b, b1b, A, nullptr, N);
            gin_layer_fused<false><<<layerGrid, 256, 0, stream>>>(
                A, nullptr, rowptr, esrc, eps2, W2a, b2a, W2b, b2b, out, nullptr, N);
        }
    } else {
        // ---- fallback: R1 atomic-scatter path ----
        int initGrid = (n4 + 255) / 256;
        int scatGrid = (E * D4 + 255) / 256;
        int gemmGrid = (N + 63) / 64;
        init_scale<<<initGrid, 256, 0, stream>>>(feat, eps1, A, n4);
        scatter_add<<<scatGrid, 256, 0, stream>>>(feat, src, dst, A, E);
        gemm_relu<<<gemmGrid, 256, 0, stream>>>(A, W1a, b1a, out, N);
        gemm_relu<<<gemmGrid, 256, 0, stream>>>(out, W1b, b1b, A, N);
        init_scale<<<initGrid, 256, 0, stream>>>(A, eps2, out, n4);
        scatter_add<<<scatGrid, 256, 0, stream>>>(A, src, dst, out, E);
        gemm_relu<<<gemmGrid, 256, 0, stream>>>(out, W2a, b2a, A, N);
        gemm_relu<<<gemmGrid, 256, 0, stream>>>(A, W2b, b2b, out, N);
    }
}